// Round 4
// baseline (160.307 us; speedup 1.0000x reference)
//
#include <hip/hip_runtime.h>
#include <math.h>

// ProductManifoldPhasorBlock — R10: revert R9's retrieve_out fusion (64-block
// grid lost more to parallelism than the 8MB round-trip saved; R8=156.3 vs
// R9=159.0) back to the R8 5-dispatch structure, plus gemm1 with 128x64
// m-tiles (grid 32,4,5): halves B-pack/B-fetch per output element in the
// staging-bound first GEMM. MFMA sequences per output unchanged -> bit-
// identical results. 5 dispatches:
//  1) gemm1       : 5x (MLP1 GELU -> h bf16) + (V proj -> VT bf16), 128x64 tiles
//  2) gemm2p      : 4x MLP2 + tanh*scale + phasor + PhiKT transpose
//  3) kv_prefix   : per-chunk KV sums (MFMA) + in-register exclusive prefix -> SpreB bf16
//  4) retrieve    : PhiQ@Spre^T + tril(PhiQ@PhiK^T)@V (MFMA) -> r fp32
//  5) out_ln_gemm : LayerNorm in A-staging + out proj + residual -> d_out
// Model: dur ≈ ~123µs harness floor (3x 256MiB re-poison fills @ ~82% HBM
// peak, untouchable) + kernel_sum (~30µs). Lesson (R9): fusions that shrink
// the grid below ~128 blocks cost more than the traffic they save.

#define Bn 4
#define Ln 1024
#define BLn 4096

typedef __attribute__((ext_vector_type(8))) short bf16x8;
typedef __attribute__((ext_vector_type(4))) float f32x4;

__device__ inline ushort f2bf(float f) {
  union { float f; uint u; } x; x.f = f;
  uint r = x.u + 0x7fffu + ((x.u >> 16) & 1u);
  return (ushort)(r >> 16);
}
__device__ inline uint pk2(float a, float b) {
  return (uint)f2bf(a) | ((uint)f2bf(b) << 16);
}

// --------------------------------------------------- gemm1 (cast + MFMA)
// 128x64 m-tile: 4 waves, each owns a 32-row strip x all 64 cols.
// act 1: GELU -> bf16 Y[4096][256]; act 4: bf16 transposed -> VT[256][4096]
struct G1Prob { const float* X; const float* W; const float* bias; void* Y; int act; };
struct G1Args { G1Prob p[5]; };

__global__ __launch_bounds__(256) void gemm1(G1Args args) {
  const G1Prob p = args.p[blockIdx.z];
  __shared__ ushort As[128 * 40];
  __shared__ ushort Bs[64 * 40];
  const int tid = threadIdx.x;
  const int m0 = blockIdx.x * 128, n0 = blockIdx.y * 64;
  const int lane = tid & 63, w = tid >> 6;
  const int fr = lane & 15, quad = lane >> 4;
  f32x4 acc[2][4];
#pragma unroll
  for (int i = 0; i < 2; i++)
#pragma unroll
    for (int j = 0; j < 4; j++) acc[i][j] = (f32x4){0.f, 0.f, 0.f, 0.f};

  const int srA = tid >> 1, scA = (tid & 1) * 16;   // 128 rows x 32 k
  const int srB = tid >> 2, scB = (tid & 3) * 8;    // 64 rows x 32 k
  for (int k0 = 0; k0 < 256; k0 += 32) {
    const float* xa = p.X + (size_t)(m0 + srA) * 256 + k0 + scA;
    float4 a0 = *(const float4*)(xa + 0);
    float4 a1 = *(const float4*)(xa + 4);
    float4 a2 = *(const float4*)(xa + 8);
    float4 a3 = *(const float4*)(xa + 12);
    float4 b0 = *(const float4*)(p.W + (size_t)(n0 + srB) * 256 + k0 + scB);
    float4 b1 = *(const float4*)(p.W + (size_t)(n0 + srB) * 256 + k0 + scB + 4);
    uint4 pa0 = { pk2(a0.x, a0.y), pk2(a0.z, a0.w), pk2(a1.x, a1.y), pk2(a1.z, a1.w) };
    uint4 pa1 = { pk2(a2.x, a2.y), pk2(a2.z, a2.w), pk2(a3.x, a3.y), pk2(a3.z, a3.w) };
    uint4 pb  = { pk2(b0.x, b0.y), pk2(b0.z, b0.w), pk2(b1.x, b1.y), pk2(b1.z, b1.w) };
    *(uint4*)&As[srA * 40 + scA] = pa0;
    *(uint4*)&As[srA * 40 + scA + 8] = pa1;
    *(uint4*)&Bs[srB * 40 + scB] = pb;
    __syncthreads();
    bf16x8 fa[2], fb[4];
#pragma unroll
    for (int i = 0; i < 2; i++)
      fa[i] = *(const bf16x8*)&As[(w * 32 + i * 16 + fr) * 40 + quad * 8];
#pragma unroll
    for (int j = 0; j < 4; j++)
      fb[j] = *(const bf16x8*)&Bs[(j * 16 + fr) * 40 + quad * 8];
#pragma unroll
    for (int i = 0; i < 2; i++)
#pragma unroll
      for (int j = 0; j < 4; j++)
        acc[i][j] = __builtin_amdgcn_mfma_f32_16x16x32_bf16(fa[i], fb[j], acc[i][j], 0, 0, 0);
    __syncthreads();
  }
#pragma unroll
  for (int i = 0; i < 2; i++)
#pragma unroll
    for (int j = 0; j < 4; j++) {
      int col = n0 + j * 16 + fr;
      float bv = p.bias[col];
      if (p.act == 4) {
        int rowg0 = m0 + w * 32 + i * 16 + quad * 4;
        ushort4 st;
        st.x = f2bf(acc[i][j][0] + bv);
        st.y = f2bf(acc[i][j][1] + bv);
        st.z = f2bf(acc[i][j][2] + bv);
        st.w = f2bf(acc[i][j][3] + bv);
        *(ushort4*)((ushort*)p.Y + (size_t)col * 4096 + rowg0) = st;
      } else {
#pragma unroll
        for (int r = 0; r < 4; r++) {
          int rowg = m0 + w * 32 + i * 16 + quad * 4 + r;
          float o = acc[i][j][r] + bv;
          o = 0.5f * o * (1.0f + erff(o * 0.70710678118654752f));
          ((ushort*)p.Y)[(size_t)rowg * 256 + col] = f2bf(o);
        }
      }
    }
}

// ---------------------------- gemm2p (MLP2 + tanh*scale + phasor + PhiKT)
// z=0: kp periodic  -> PhiK cols 0..47, PhiKT rows 0..95 (doT)
// z=1: qp periodic  -> PhiQ cols 0..47
// z=2: kh hyperbolic-> PhiK cols 48..63, PhiKT rows 96..127 (doT)
// z=3: qh hyperbolic-> PhiQ cols 48..63
struct G2P { const ushort* X; const float* W; const float* bias; uint* Phi;
             int Nreal; float scale; int doT; int isHyp; };
struct G2Args { G2P p[4]; };

__global__ __launch_bounds__(256) void gemm2p(G2Args args, uint* PhiKT) {
  const G2P p = args.p[blockIdx.z];
  __shared__ ushort As[64 * 40];
  __shared__ ushort Bs[64 * 40];
  __shared__ ushort LK[64][130];
  const int tid = threadIdx.x;
  const int m0 = blockIdx.x * 64;
  const int lane = tid & 63, wave = tid >> 6;
  const int wr = wave >> 1, wc = wave & 1;
  const int fr = lane & 15, quad = lane >> 4;
  f32x4 acc[2][2];
#pragma unroll
  for (int i = 0; i < 2; i++)
#pragma unroll
    for (int j = 0; j < 2; j++) acc[i][j] = (f32x4){0.f, 0.f, 0.f, 0.f};

  const int srow = tid >> 2, sch = (tid & 3) * 8;
  for (int k0 = 0; k0 < 256; k0 += 32) {
    uint4 pa = *(const uint4*)(p.X + (size_t)(m0 + srow) * 256 + k0 + sch);
    float4 b0 = {0.f,0.f,0.f,0.f}, b1 = {0.f,0.f,0.f,0.f};
    if (srow < p.Nreal) {
      b0 = *(const float4*)(p.W + (size_t)srow * 256 + k0 + sch);
      b1 = *(const float4*)(p.W + (size_t)srow * 256 + k0 + sch + 4);
    }
    uint4 pb = { pk2(b0.x, b0.y), pk2(b0.z, b0.w), pk2(b1.x, b1.y), pk2(b1.z, b1.w) };
    *(uint4*)&As[srow * 40 + sch] = pa;
    *(uint4*)&Bs[srow * 40 + sch] = pb;
    __syncthreads();
    bf16x8 fa0 = *(const bf16x8*)&As[(wr * 32 + fr) * 40 + quad * 8];
    bf16x8 fa1 = *(const bf16x8*)&As[(wr * 32 + 16 + fr) * 40 + quad * 8];
    bf16x8 fb0 = *(const bf16x8*)&Bs[(wc * 32 + fr) * 40 + quad * 8];
    bf16x8 fb1 = *(const bf16x8*)&Bs[(wc * 32 + 16 + fr) * 40 + quad * 8];
    acc[0][0] = __builtin_amdgcn_mfma_f32_16x16x32_bf16(fa0, fb0, acc[0][0], 0, 0, 0);
    acc[0][1] = __builtin_amdgcn_mfma_f32_16x16x32_bf16(fa0, fb1, acc[0][1], 0, 0, 0);
    acc[1][0] = __builtin_amdgcn_mfma_f32_16x16x32_bf16(fa1, fb0, acc[1][0], 0, 0, 0);
    acc[1][1] = __builtin_amdgcn_mfma_f32_16x16x32_bf16(fa1, fb1, acc[1][1], 0, 0, 0);
    __syncthreads();
  }

  // epilogue: tanh*scale -> phasor -> PhiQ/PhiK (+ LK staging for PhiKT)
#pragma unroll
  for (int i = 0; i < 2; i++)
#pragma unroll
    for (int j = 0; j < 2; j++) {
      int col = wc * 32 + j * 16 + fr;
      float bv = (col < p.Nreal) ? p.bias[col] : 0.f;
#pragma unroll
      for (int r = 0; r < 4; r++) {
        int rowl = wr * 32 + i * 16 + quad * 4 + r;
        int row = m0 + rowl;
        float t = tanhf(acc[i][j][r] + bv) * p.scale;
        if (!p.isHyp) {
          if (col < p.Nreal) {
            float im, re;
            __sincosf(t, &im, &re);
            uint pk = pk2(re, im);
            p.Phi[(size_t)row * 64 + col] = pk;
            if (p.doT) *(uint*)&LK[rowl][2 * col] = pk;
          }
        } else {
          float tp = __shfl_xor(t, 1);          // partner component (col^1)
          if ((col & 1) == 0 && col < p.Nreal) {
            float av = t, bw = tp;
            float rr = sqrtf(av * av + bw * bw);
            float re, im;
            if (rr > 0.f) { float inv = (1.0f - rr) / rr; re = av * inv; im = bw * inv; }
            else          { re = 1.0f; im = 0.0f; }
            int k = 48 + (col >> 1);
            uint pk = pk2(re, im);
            p.Phi[(size_t)row * 64 + k] = pk;
            if (p.doT) *(uint*)&LK[rowl][2 * k] = pk;
          }
        }
      }
    }

  // transposed PhiKT writes (K problems only)
  if (p.doT) {
    __syncthreads();
    const int b = m0 >> 10, lb0 = m0 & 1023;
    const int nk2 = p.isHyp ? 32 : 96;
    const int k2base = p.isHyp ? 96 : 0;
    const int tot = nk2 * 32;
    for (int idx = tid; idx < tot; idx += 256) {
      int k2 = k2base + (idx >> 5), lp = idx & 31;
      uint v = (uint)LK[lp * 2][k2] | ((uint)LK[lp * 2 + 1][k2] << 16);
      PhiKT[(size_t)b * 65536 + k2 * 512 + (lb0 >> 1) + lp] = v;
    }
  }
}

// --------------------------------------- kv chunks + exclusive chunk prefix
// SpreB[b*16+c][d][k2] = bf16( sum_{c'<c} sum_{l in c'} V[l][d]*PhiK[l][k2] ).
__global__ __launch_bounds__(256) void kv_prefix(const ushort* VT, const ushort* PhiKT,
                                                 ushort* SpreB) {
  const int b = blockIdx.x >> 4, ds = blockIdx.x & 15;
  const int d0 = ds * 16;
  const int tid = threadIdx.x, lane = tid & 63, wave = tid >> 6;
  const int fr = lane & 15, quad = lane >> 4;
  const int k2b = blockIdx.y * 64 + wave * 16;
  const ushort* pA = PhiKT + (size_t)b * 131072 + (size_t)(k2b + fr) * 1024;
  const ushort* pB = VT + (size_t)(d0 + fr) * 4096 + b * 1024;
  ushort* outp = SpreB + ((size_t)(b * 16) * 256 + d0 + fr) * 128 + k2b + quad * 4;
  f32x4 carry = (f32x4){0.f, 0.f, 0.f, 0.f};
#pragma unroll 4
  for (int c = 0; c < 16; c++) {
    bf16x8 a0 = *(const bf16x8*)(pA + c * 64 + quad * 8);
    bf16x8 b0 = *(const bf16x8*)(pB + c * 64 + quad * 8);
    bf16x8 a1 = *(const bf16x8*)(pA + c * 64 + 32 + quad * 8);
    bf16x8 b1 = *(const bf16x8*)(pB + c * 64 + 32 + quad * 8);
    ushort4 st;
    st.x = f2bf(carry[0]); st.y = f2bf(carry[1]);
    st.z = f2bf(carry[2]); st.w = f2bf(carry[3]);
    *(ushort4*)outp = st;
    outp += 32768;                       // next chunk: +256*128 ushorts
    f32x4 acc = (f32x4){0.f, 0.f, 0.f, 0.f};
    acc = __builtin_amdgcn_mfma_f32_16x16x32_bf16(a0, b0, acc, 0, 0, 0);
    acc = __builtin_amdgcn_mfma_f32_16x16x32_bf16(a1, b1, acc, 0, 0, 0);
    carry += acc;
  }
}

// --------------------------------------------------------------- retrieve
// O = PhiQ @ SpreB^T + tril(PhiQ @ PhiK^T) @ V, scaled; grid (64, 2), 4 waves.
__global__ __launch_bounds__(256) void retrieve(const ushort* PhiQ, const ushort* PhiK,
                                                const ushort* VT, const ushort* SpreB,
                                                float* R) {
  __shared__ ushort Sl[64 * 72];
  const int bc = blockIdx.x;
  const int b = bc >> 4, c = bc & 15;
  const int d0 = blockIdx.y * 128;
  const int tid = threadIdx.x, lane = tid & 63, wy = tid >> 6;
  const int fr = lane & 15, quad = lane >> 4;
  const int g0 = b * 1024 + c * 64;
  bf16x8 a[4][4];
#pragma unroll
  for (int i = 0; i < 4; i++)
#pragma unroll
    for (int kk = 0; kk < 4; kk++)
      a[i][kk] = *(const bf16x8*)(PhiQ + (size_t)(g0 + i * 16 + fr) * 128 + kk * 32 + quad * 8);

  f32x4 acc[4][2];
#pragma unroll
  for (int i = 0; i < 4; i++)
#pragma unroll
    for (int j = 0; j < 2; j++) acc[i][j] = (f32x4){0.f, 0.f, 0.f, 0.f};

  // inter-chunk: PhiQ @ SpreB^T
#pragma unroll
  for (int kk = 0; kk < 4; kk++) {
    bf16x8 bb[2];
#pragma unroll
    for (int j = 0; j < 2; j++)
      bb[j] = *(const bf16x8*)(SpreB + ((size_t)bc * 256 + d0 + wy * 32 + j * 16 + fr) * 128 + kk * 32 + quad * 8);
#pragma unroll
    for (int i = 0; i < 4; i++)
#pragma unroll
      for (int j = 0; j < 2; j++)
        acc[i][j] = __builtin_amdgcn_mfma_f32_16x16x32_bf16(a[i][kk], bb[j], acc[i][j], 0, 0, 0);
  }

  // intra-chunk scores: wave wy computes 16-col strip of S (64x64)
  f32x4 sacc[4];
#pragma unroll
  for (int i = 0; i < 4; i++) sacc[i] = (f32x4){0.f, 0.f, 0.f, 0.f};
#pragma unroll
  for (int kk = 0; kk < 4; kk++) {
    bf16x8 bs = *(const bf16x8*)(PhiK + (size_t)(g0 + wy * 16 + fr) * 128 + kk * 32 + quad * 8);
#pragma unroll
    for (int i = 0; i < 4; i++)
      sacc[i] = __builtin_amdgcn_mfma_f32_16x16x32_bf16(a[i][kk], bs, sacc[i], 0, 0, 0);
  }
#pragma unroll
  for (int i = 0; i < 4; i++)
#pragma unroll
    for (int r = 0; r < 4; r++) {
      int row = i * 16 + quad * 4 + r;
      int col = wy * 16 + fr;
      Sl[row * 72 + col] = (col <= row) ? f2bf(sacc[i][r]) : (ushort)0;
    }
  __syncthreads();

  // intra-chunk PV: tril(S) @ V
#pragma unroll
  for (int kk = 0; kk < 2; kk++) {
    bf16x8 as[4], bv[2];
#pragma unroll
    for (int i = 0; i < 4; i++)
      as[i] = *(const bf16x8*)&Sl[(i * 16 + fr) * 72 + kk * 32 + quad * 8];
#pragma unroll
    for (int j = 0; j < 2; j++)
      bv[j] = *(const bf16x8*)(VT + (size_t)(d0 + wy * 32 + j * 16 + fr) * 4096 + g0 + kk * 32 + quad * 8);
#pragma unroll
    for (int i = 0; i < 4; i++)
#pragma unroll
      for (int j = 0; j < 2; j++)
        acc[i][j] = __builtin_amdgcn_mfma_f32_16x16x32_bf16(as[i], bv[j], acc[i][j], 0, 0, 0);
  }

#pragma unroll
  for (int i = 0; i < 4; i++)
#pragma unroll
    for (int j = 0; j < 2; j++)
#pragma unroll
      for (int r = 0; r < 4; r++) {
        int row = i * 16 + quad * 4 + r;
        int d = d0 + wy * 32 + j * 16 + fr;
        float scale = rsqrtf((float)((c * 64 + row + 1) * 64));
        R[(size_t)(g0 + row) * 256 + d] = acc[i][j][r] * scale;
      }
}

// ----------------------------------------- LayerNorm + out proj + residual
__global__ __launch_bounds__(256) void out_ln_gemm(const float* r, const float* g,
                                                   const float* bta, const float* W,
                                                   const float* ob, const float* x,
                                                   float* Y) {
  __shared__ ushort A_lds[64 * 272];
  __shared__ ushort Bs[64 * 40];
  __shared__ float gs[256], bs2[256];
  const int tid = threadIdx.x;
  const int m0 = blockIdx.x * 64, n0 = blockIdx.y * 64;
  gs[tid] = g[tid];
  bs2[tid] = bta[tid];

  const int row_l = tid >> 2, seg = (tid & 3) * 64;
  const float* rr = r + (size_t)(m0 + row_l) * 256 + seg;
  float s = 0.f, sq = 0.f;
#pragma unroll
  for (int i = 0; i < 64; i += 4) {
    float4 v = *(const float4*)(rr + i);
    s += v.x + v.y + v.z + v.w;
    sq += v.x * v.x + v.y * v.y + v.z * v.z + v.w * v.w;
  }
  s += __shfl_xor(s, 1); sq += __shfl_xor(sq, 1);
  s += __shfl_xor(s, 2); sq += __shfl_xor(sq, 2);
  float mean = s * (1.0f / 256.0f);
  float var = fmaxf(sq * (1.0f / 256.0f) - mean * mean, 0.f);
  float rstd = rsqrtf(var + 1e-5f);
  __syncthreads();
#pragma unroll
  for (int i = 0; i < 64; i += 4) {
    float4 v = *(const float4*)(rr + i);
    int k = seg + i;
    ushort4 st;
    st.x = f2bf((v.x - mean) * rstd * gs[k + 0] + bs2[k + 0]);
    st.y = f2bf((v.y - mean) * rstd * gs[k + 1] + bs2[k + 1]);
    st.z = f2bf((v.z - mean) * rstd * gs[k + 2] + bs2[k + 2]);
    st.w = f2bf((v.w - mean) * rstd * gs[k + 3] + bs2[k + 3]);
    *(ushort4*)&A_lds[row_l * 272 + k] = st;
  }
  __syncthreads();

  const int lane = tid & 63, wave = tid >> 6;
  const int wr = wave >> 1, wc = wave & 1;
  const int fr = lane & 15, quad = lane >> 4;
  const int srow = tid >> 2, sch = (tid & 3) * 8;
  f32x4 acc[2][2];
#pragma unroll
  for (int i = 0; i < 2; i++)
#pragma unroll
    for (int j = 0; j < 2; j++) acc[i][j] = (f32x4){0.f, 0.f, 0.f, 0.f};
  for (int k0 = 0; k0 < 256; k0 += 32) {
    float4 b0 = *(const float4*)(W + (size_t)(n0 + srow) * 256 + k0 + sch);
    float4 b1 = *(const float4*)(W + (size_t)(n0 + srow) * 256 + k0 + sch + 4);
    uint4 pb = { pk2(b0.x, b0.y), pk2(b0.z, b0.w), pk2(b1.x, b1.y), pk2(b1.z, b1.w) };
    *(uint4*)&Bs[srow * 40 + sch] = pb;
    __syncthreads();
    bf16x8 fa0 = *(const bf16x8*)&A_lds[(wr * 32 + fr) * 272 + k0 + quad * 8];
    bf16x8 fa1 = *(const bf16x8*)&A_lds[(wr * 32 + 16 + fr) * 272 + k0 + quad * 8];
    bf16x8 fb0 = *(const bf16x8*)&Bs[(wc * 32 + fr) * 40 + quad * 8];
    bf16x8 fb1 = *(const bf16x8*)&Bs[(wc * 32 + 16 + fr) * 40 + quad * 8];
    acc[0][0] = __builtin_amdgcn_mfma_f32_16x16x32_bf16(fa0, fb0, acc[0][0], 0, 0, 0);
    acc[0][1] = __builtin_amdgcn_mfma_f32_16x16x32_bf16(fa0, fb1, acc[0][1], 0, 0, 0);
    acc[1][0] = __builtin_amdgcn_mfma_f32_16x16x32_bf16(fa1, fb0, acc[1][0], 0, 0, 0);
    acc[1][1] = __builtin_amdgcn_mfma_f32_16x16x32_bf16(fa1, fb1, acc[1][1], 0, 0, 0);
    __syncthreads();
  }
#pragma unroll
  for (int i = 0; i < 2; i++)
#pragma unroll
    for (int j = 0; j < 2; j++) {
      int col = n0 + wc * 32 + j * 16 + fr;
      float bv = ob[col];
#pragma unroll
      for (int r = 0; r < 4; r++) {
        int rowg = m0 + wr * 32 + i * 16 + quad * 4 + r;
        Y[(size_t)rowg * 256 + col] = acc[i][j][r] + bv + x[(size_t)rowg * 256 + col];
      }
    }
}

// ------------------------------------------------------------------- launch
extern "C" void kernel_launch(void* const* d_in, const int* in_sizes, int n_in,
                              void* d_out, int out_size, void* d_ws, size_t ws_size,
                              hipStream_t stream) {
  const float* x     = (const float*)d_in[0];
  const float* kp_w1 = (const float*)d_in[1];
  const float* kp_b1 = (const float*)d_in[2];
  const float* kp_w2 = (const float*)d_in[3];
  const float* kp_b2 = (const float*)d_in[4];
  const float* qp_w1 = (const float*)d_in[5];
  const float* qp_b1 = (const float*)d_in[6];
  const float* qp_w2 = (const float*)d_in[7];
  const float* qp_b2 = (const float*)d_in[8];
  const float* kh_w1 = (const float*)d_in[9];
  const float* kh_b1 = (const float*)d_in[10];
  const float* kh_w2 = (const float*)d_in[11];
  const float* kh_b2 = (const float*)d_in[12];
  const float* qh_w1 = (const float*)d_in[13];
  const float* qh_b1 = (const float*)d_in[14];
  const float* qh_w2 = (const float*)d_in[15];
  const float* qh_b2 = (const float*)d_in[16];
  const float* v_w   = (const float*)d_in[17];
  const float* v_b   = (const float*)d_in[18];
  const float* ln_g  = (const float*)d_in[19];
  const float* ln_b  = (const float*)d_in[20];
  const float* out_w = (const float*)d_in[21];
  const float* out_b = (const float*)d_in[22];

  char* ws = (char*)d_ws;
  const size_t MiB = 1024 * 1024;
  ushort* h0   = (ushort*)(ws + 0);            // [4096][256] bf16, 2 MiB each
  ushort* h1   = (ushort*)(ws + 2 * MiB);
  ushort* h2   = (ushort*)(ws + 4 * MiB);
  ushort* h3   = (ushort*)(ws + 6 * MiB);
  ushort* VT   = (ushort*)(ws + 8 * MiB);      // [256][4096] bf16, 2 MiB
  uint*   PhiQ = (uint*)(ws + 10 * MiB);       // [4096][64] packed, 1 MiB
  uint*   PhiK = (uint*)(ws + 11 * MiB);       // 1 MiB
  uint*   PhiKT= (uint*)(ws + 12 * MiB);       // [4][128][512], 1 MiB
  ushort* SpreB= (ushort*)(ws + 25 * MiB);     // [64][256][128] bf16, 4 MiB
  float*  r    = (float*)(ws + 29 * MiB);      // [4096][256] fp32, 4 MiB

  // 1) first layers + V projection (fp32 inputs, in-kernel cast), 128x64 tiles
  G1Args g1;
  g1.p[0] = { x, kp_w1, kp_b1, h0, 1 };
  g1.p[1] = { x, qp_w1, qp_b1, h1, 1 };
  g1.p[2] = { x, kh_w1, kh_b1, h2, 1 };
  g1.p[3] = { x, qh_w1, qh_b1, h3, 1 };
  g1.p[4] = { x, v_w,   v_b,   VT, 4 };
  gemm1<<<dim3(32, 4, 5), 256, 0, stream>>>(g1);

  // 2) second layers + phasors + PhiKT, z-parallel (N=64 padded)
  const float PI_F = 3.14159265358979323846f;
  G2Args g2;
  g2.p[0] = { h0, kp_w2, kp_b2, PhiK, 48, PI_F, 1, 0 };
  g2.p[1] = { h1, qp_w2, qp_b2, PhiQ, 48, PI_F, 0, 0 };
  g2.p[2] = { h2, kh_w2, kh_b2, PhiK, 32, 0.9f, 1, 1 };
  g2.p[3] = { h3, qh_w2, qh_b2, PhiQ, 32, 0.9f, 0, 1 };
  gemm2p<<<dim3(64, 1, 4), 256, 0, stream>>>(g2, PhiKT);

  // 3) per-chunk KV sums + exclusive chunk prefix (fused, registers carry)
  kv_prefix<<<dim3(64, 2), 256, 0, stream>>>(VT, (const ushort*)PhiKT, SpreB);

  // 4) retrieve (MFMA)
  retrieve<<<dim3(64, 2), 256, 0, stream>>>((const ushort*)PhiQ, (const ushort*)PhiK,
                                            VT, SpreB, r);

  // 5) LayerNorm + out projection + residual
  out_ln_gemm<<<dim3(64, 4), 256, 0, stream>>>(r, ln_g, ln_b, out_w, out_b, x,
                                               (float*)d_out);
}

// Round 6
// 153.177 us; speedup vs baseline: 1.0465x; 1.0465x over previous
//
#include <hip/hip_runtime.h>
#include <math.h>

// ProductManifoldPhasorBlock — R12: identical resubmit of R11 (= R8 structure,
// best measured: 156.3µs, absmax 0.03125). R5/round-5 bench failed on infra
// ("MI355X container failed twice"), not kernel correctness — no code change.
// 5 dispatches:
//  1) gemm1       : 5x (MLP1 GELU -> h bf16) + (V proj -> VT bf16), fp32 in-kernel cast
//  2) gemm2p      : 4x MLP2 + tanh*scale + phasor + PhiKT transpose (z-parallel)
//  3) kv_prefix   : per-chunk KV sums (MFMA) + in-register exclusive prefix -> SpreB bf16
//  4) retrieve    : PhiQ@Spre^T + tril(PhiQ@PhiK^T)@V (MFMA) -> r fp32
//  5) out_ln_gemm : LayerNorm in A-staging + out proj + residual -> d_out
// Roofline case: profile dominated by 3x 256MiB harness re-poison fills
// (~41µs each @ 82-84% HBM peak = measured achievable ceiling); kernel DAG
// ~33µs at serial dependency depth; R9 (fusion, 64-block grid) = 159.0 and
// R10 (128x64 gemm1 tiles) = 160.3 both regressed vs R8 = 156.3.

#define Bn 4
#define Ln 1024
#define BLn 4096

typedef __attribute__((ext_vector_type(8))) short bf16x8;
typedef __attribute__((ext_vector_type(4))) float f32x4;

__device__ inline ushort f2bf(float f) {
  union { float f; uint u; } x; x.f = f;
  uint r = x.u + 0x7fffu + ((x.u >> 16) & 1u);
  return (ushort)(r >> 16);
}
__device__ inline uint pk2(float a, float b) {
  return (uint)f2bf(a) | ((uint)f2bf(b) << 16);
}

// --------------------------------------------------- gemm1 (cast + MFMA)
// act 1: GELU -> bf16 Y[4096][256]; act 4: bf16 transposed -> VT[256][4096]
struct G1Prob { const float* X; const float* W; const float* bias; void* Y; int act; };
struct G1Args { G1Prob p[5]; };

__global__ __launch_bounds__(256) void gemm1(G1Args args) {
  const G1Prob p = args.p[blockIdx.z];
  __shared__ ushort As[64 * 40];
  __shared__ ushort Bs[64 * 40];
  const int tid = threadIdx.x;
  const int m0 = blockIdx.x * 64, n0 = blockIdx.y * 64;
  const int lane = tid & 63, wave = tid >> 6;
  const int wr = wave >> 1, wc = wave & 1;
  const int fr = lane & 15, quad = lane >> 4;
  f32x4 acc[2][2];
#pragma unroll
  for (int i = 0; i < 2; i++)
#pragma unroll
    for (int j = 0; j < 2; j++) acc[i][j] = (f32x4){0.f, 0.f, 0.f, 0.f};

  const int srow = tid >> 2, sch = (tid & 3) * 8;
  for (int k0 = 0; k0 < 256; k0 += 32) {
    float4 a0 = *(const float4*)(p.X + (size_t)(m0 + srow) * 256 + k0 + sch);
    float4 a1 = *(const float4*)(p.X + (size_t)(m0 + srow) * 256 + k0 + sch + 4);
    float4 b0 = *(const float4*)(p.W + (size_t)(n0 + srow) * 256 + k0 + sch);
    float4 b1 = *(const float4*)(p.W + (size_t)(n0 + srow) * 256 + k0 + sch + 4);
    uint4 pa = { pk2(a0.x, a0.y), pk2(a0.z, a0.w), pk2(a1.x, a1.y), pk2(a1.z, a1.w) };
    uint4 pb = { pk2(b0.x, b0.y), pk2(b0.z, b0.w), pk2(b1.x, b1.y), pk2(b1.z, b1.w) };
    *(uint4*)&As[srow * 40 + sch] = pa;
    *(uint4*)&Bs[srow * 40 + sch] = pb;
    __syncthreads();
    bf16x8 fa0 = *(const bf16x8*)&As[(wr * 32 + fr) * 40 + quad * 8];
    bf16x8 fa1 = *(const bf16x8*)&As[(wr * 32 + 16 + fr) * 40 + quad * 8];
    bf16x8 fb0 = *(const bf16x8*)&Bs[(wc * 32 + fr) * 40 + quad * 8];
    bf16x8 fb1 = *(const bf16x8*)&Bs[(wc * 32 + 16 + fr) * 40 + quad * 8];
    acc[0][0] = __builtin_amdgcn_mfma_f32_16x16x32_bf16(fa0, fb0, acc[0][0], 0, 0, 0);
    acc[0][1] = __builtin_amdgcn_mfma_f32_16x16x32_bf16(fa0, fb1, acc[0][1], 0, 0, 0);
    acc[1][0] = __builtin_amdgcn_mfma_f32_16x16x32_bf16(fa1, fb0, acc[1][0], 0, 0, 0);
    acc[1][1] = __builtin_amdgcn_mfma_f32_16x16x32_bf16(fa1, fb1, acc[1][1], 0, 0, 0);
    __syncthreads();
  }
#pragma unroll
  for (int i = 0; i < 2; i++)
#pragma unroll
    for (int j = 0; j < 2; j++) {
      int col = n0 + wc * 32 + j * 16 + fr;
      float bv = p.bias[col];
      if (p.act == 4) {
        int rowg0 = m0 + wr * 32 + i * 16 + quad * 4;
        ushort4 st;
        st.x = f2bf(acc[i][j][0] + bv);
        st.y = f2bf(acc[i][j][1] + bv);
        st.z = f2bf(acc[i][j][2] + bv);
        st.w = f2bf(acc[i][j][3] + bv);
        *(ushort4*)((ushort*)p.Y + (size_t)col * 4096 + rowg0) = st;
      } else {
#pragma unroll
        for (int r = 0; r < 4; r++) {
          int rowg = m0 + wr * 32 + i * 16 + quad * 4 + r;
          float o = acc[i][j][r] + bv;
          o = 0.5f * o * (1.0f + erff(o * 0.70710678118654752f));
          ((ushort*)p.Y)[(size_t)rowg * 256 + col] = f2bf(o);
        }
      }
    }
}

// ---------------------------- gemm2p (MLP2 + tanh*scale + phasor + PhiKT)
// z=0: kp periodic  -> PhiK cols 0..47, PhiKT rows 0..95 (doT)
// z=1: qp periodic  -> PhiQ cols 0..47
// z=2: kh hyperbolic-> PhiK cols 48..63, PhiKT rows 96..127 (doT)
// z=3: qh hyperbolic-> PhiQ cols 48..63
struct G2P { const ushort* X; const float* W; const float* bias; uint* Phi;
             int Nreal; float scale; int doT; int isHyp; };
struct G2Args { G2P p[4]; };

__global__ __launch_bounds__(256) void gemm2p(G2Args args, uint* PhiKT) {
  const G2P p = args.p[blockIdx.z];
  __shared__ ushort As[64 * 40];
  __shared__ ushort Bs[64 * 40];
  __shared__ ushort LK[64][130];
  const int tid = threadIdx.x;
  const int m0 = blockIdx.x * 64;
  const int lane = tid & 63, wave = tid >> 6;
  const int wr = wave >> 1, wc = wave & 1;
  const int fr = lane & 15, quad = lane >> 4;
  f32x4 acc[2][2];
#pragma unroll
  for (int i = 0; i < 2; i++)
#pragma unroll
    for (int j = 0; j < 2; j++) acc[i][j] = (f32x4){0.f, 0.f, 0.f, 0.f};

  const int srow = tid >> 2, sch = (tid & 3) * 8;
  for (int k0 = 0; k0 < 256; k0 += 32) {
    uint4 pa = *(const uint4*)(p.X + (size_t)(m0 + srow) * 256 + k0 + sch);
    float4 b0 = {0.f,0.f,0.f,0.f}, b1 = {0.f,0.f,0.f,0.f};
    if (srow < p.Nreal) {
      b0 = *(const float4*)(p.W + (size_t)srow * 256 + k0 + sch);
      b1 = *(const float4*)(p.W + (size_t)srow * 256 + k0 + sch + 4);
    }
    uint4 pb = { pk2(b0.x, b0.y), pk2(b0.z, b0.w), pk2(b1.x, b1.y), pk2(b1.z, b1.w) };
    *(uint4*)&As[srow * 40 + sch] = pa;
    *(uint4*)&Bs[srow * 40 + sch] = pb;
    __syncthreads();
    bf16x8 fa0 = *(const bf16x8*)&As[(wr * 32 + fr) * 40 + quad * 8];
    bf16x8 fa1 = *(const bf16x8*)&As[(wr * 32 + 16 + fr) * 40 + quad * 8];
    bf16x8 fb0 = *(const bf16x8*)&Bs[(wc * 32 + fr) * 40 + quad * 8];
    bf16x8 fb1 = *(const bf16x8*)&Bs[(wc * 32 + 16 + fr) * 40 + quad * 8];
    acc[0][0] = __builtin_amdgcn_mfma_f32_16x16x32_bf16(fa0, fb0, acc[0][0], 0, 0, 0);
    acc[0][1] = __builtin_amdgcn_mfma_f32_16x16x32_bf16(fa0, fb1, acc[0][1], 0, 0, 0);
    acc[1][0] = __builtin_amdgcn_mfma_f32_16x16x32_bf16(fa1, fb0, acc[1][0], 0, 0, 0);
    acc[1][1] = __builtin_amdgcn_mfma_f32_16x16x32_bf16(fa1, fb1, acc[1][1], 0, 0, 0);
    __syncthreads();
  }

  // epilogue: tanh*scale -> phasor -> PhiQ/PhiK (+ LK staging for PhiKT)
#pragma unroll
  for (int i = 0; i < 2; i++)
#pragma unroll
    for (int j = 0; j < 2; j++) {
      int col = wc * 32 + j * 16 + fr;
      float bv = (col < p.Nreal) ? p.bias[col] : 0.f;
#pragma unroll
      for (int r = 0; r < 4; r++) {
        int rowl = wr * 32 + i * 16 + quad * 4 + r;
        int row = m0 + rowl;
        float t = tanhf(acc[i][j][r] + bv) * p.scale;
        if (!p.isHyp) {
          if (col < p.Nreal) {
            float im, re;
            __sincosf(t, &im, &re);
            uint pk = pk2(re, im);
            p.Phi[(size_t)row * 64 + col] = pk;
            if (p.doT) *(uint*)&LK[rowl][2 * col] = pk;
          }
        } else {
          float tp = __shfl_xor(t, 1);          // partner component (col^1)
          if ((col & 1) == 0 && col < p.Nreal) {
            float av = t, bw = tp;
            float rr = sqrtf(av * av + bw * bw);
            float re, im;
            if (rr > 0.f) { float inv = (1.0f - rr) / rr; re = av * inv; im = bw * inv; }
            else          { re = 1.0f; im = 0.0f; }
            int k = 48 + (col >> 1);
            uint pk = pk2(re, im);
            p.Phi[(size_t)row * 64 + k] = pk;
            if (p.doT) *(uint*)&LK[rowl][2 * k] = pk;
          }
        }
      }
    }

  // transposed PhiKT writes (K problems only)
  if (p.doT) {
    __syncthreads();
    const int b = m0 >> 10, lb0 = m0 & 1023;
    const int nk2 = p.isHyp ? 32 : 96;
    const int k2base = p.isHyp ? 96 : 0;
    const int tot = nk2 * 32;
    for (int idx = tid; idx < tot; idx += 256) {
      int k2 = k2base + (idx >> 5), lp = idx & 31;
      uint v = (uint)LK[lp * 2][k2] | ((uint)LK[lp * 2 + 1][k2] << 16);
      PhiKT[(size_t)b * 65536 + k2 * 512 + (lb0 >> 1) + lp] = v;
    }
  }
}

// --------------------------------------- kv chunks + exclusive chunk prefix
// SpreB[b*16+c][d][k2] = bf16( sum_{c'<c} sum_{l in c'} V[l][d]*PhiK[l][k2] ).
__global__ __launch_bounds__(256) void kv_prefix(const ushort* VT, const ushort* PhiKT,
                                                 ushort* SpreB) {
  const int b = blockIdx.x >> 4, ds = blockIdx.x & 15;
  const int d0 = ds * 16;
  const int tid = threadIdx.x, lane = tid & 63, wave = tid >> 6;
  const int fr = lane & 15, quad = lane >> 4;
  const int k2b = blockIdx.y * 64 + wave * 16;
  const ushort* pA = PhiKT + (size_t)b * 131072 + (size_t)(k2b + fr) * 1024;
  const ushort* pB = VT + (size_t)(d0 + fr) * 4096 + b * 1024;
  ushort* outp = SpreB + ((size_t)(b * 16) * 256 + d0 + fr) * 128 + k2b + quad * 4;
  f32x4 carry = (f32x4){0.f, 0.f, 0.f, 0.f};
#pragma unroll 4
  for (int c = 0; c < 16; c++) {
    bf16x8 a0 = *(const bf16x8*)(pA + c * 64 + quad * 8);
    bf16x8 b0 = *(const bf16x8*)(pB + c * 64 + quad * 8);
    bf16x8 a1 = *(const bf16x8*)(pA + c * 64 + 32 + quad * 8);
    bf16x8 b1 = *(const bf16x8*)(pB + c * 64 + 32 + quad * 8);
    ushort4 st;
    st.x = f2bf(carry[0]); st.y = f2bf(carry[1]);
    st.z = f2bf(carry[2]); st.w = f2bf(carry[3]);
    *(ushort4*)outp = st;
    outp += 32768;                       // next chunk: +256*128 ushorts
    f32x4 acc = (f32x4){0.f, 0.f, 0.f, 0.f};
    acc = __builtin_amdgcn_mfma_f32_16x16x32_bf16(a0, b0, acc, 0, 0, 0);
    acc = __builtin_amdgcn_mfma_f32_16x16x32_bf16(a1, b1, acc, 0, 0, 0);
    carry += acc;
  }
}

// --------------------------------------------------------------- retrieve
// O = PhiQ @ SpreB^T + tril(PhiQ @ PhiK^T) @ V, scaled; grid (64, 2), 4 waves.
__global__ __launch_bounds__(256) void retrieve(const ushort* PhiQ, const ushort* PhiK,
                                                const ushort* VT, const ushort* SpreB,
                                                float* R) {
  __shared__ ushort Sl[64 * 72];
  const int bc = blockIdx.x;
  const int b = bc >> 4, c = bc & 15;
  const int d0 = blockIdx.y * 128;
  const int tid = threadIdx.x, lane = tid & 63, wy = tid >> 6;
  const int fr = lane & 15, quad = lane >> 4;
  const int g0 = b * 1024 + c * 64;
  bf16x8 a[4][4];
#pragma unroll
  for (int i = 0; i < 4; i++)
#pragma unroll
    for (int kk = 0; kk < 4; kk++)
      a[i][kk] = *(const bf16x8*)(PhiQ + (size_t)(g0 + i * 16 + fr) * 128 + kk * 32 + quad * 8);

  f32x4 acc[4][2];
#pragma unroll
  for (int i = 0; i < 4; i++)
#pragma unroll
    for (int j = 0; j < 2; j++) acc[i][j] = (f32x4){0.f, 0.f, 0.f, 0.f};

  // inter-chunk: PhiQ @ SpreB^T
#pragma unroll
  for (int kk = 0; kk < 4; kk++) {
    bf16x8 bb[2];
#pragma unroll
    for (int j = 0; j < 2; j++)
      bb[j] = *(const bf16x8*)(SpreB + ((size_t)bc * 256 + d0 + wy * 32 + j * 16 + fr) * 128 + kk * 32 + quad * 8);
#pragma unroll
    for (int i = 0; i < 4; i++)
#pragma unroll
      for (int j = 0; j < 2; j++)
        acc[i][j] = __builtin_amdgcn_mfma_f32_16x16x32_bf16(a[i][kk], bb[j], acc[i][j], 0, 0, 0);
  }

  // intra-chunk scores: wave wy computes 16-col strip of S (64x64)
  f32x4 sacc[4];
#pragma unroll
  for (int i = 0; i < 4; i++) sacc[i] = (f32x4){0.f, 0.f, 0.f, 0.f};
#pragma unroll
  for (int kk = 0; kk < 4; kk++) {
    bf16x8 bs = *(const bf16x8*)(PhiK + (size_t)(g0 + wy * 16 + fr) * 128 + kk * 32 + quad * 8);
#pragma unroll
    for (int i = 0; i < 4; i++)
      sacc[i] = __builtin_amdgcn_mfma_f32_16x16x32_bf16(a[i][kk], bs, sacc[i], 0, 0, 0);
  }
#pragma unroll
  for (int i = 0; i < 4; i++)
#pragma unroll
    for (int r = 0; r < 4; r++) {
      int row = i * 16 + quad * 4 + r;
      int col = wy * 16 + fr;
      Sl[row * 72 + col] = (col <= row) ? f2bf(sacc[i][r]) : (ushort)0;
    }
  __syncthreads();

  // intra-chunk PV: tril(S) @ V
#pragma unroll
  for (int kk = 0; kk < 2; kk++) {
    bf16x8 as[4], bv[2];
#pragma unroll
    for (int i = 0; i < 4; i++)
      as[i] = *(const bf16x8*)&Sl[(i * 16 + fr) * 72 + kk * 32 + quad * 8];
#pragma unroll
    for (int j = 0; j < 2; j++)
      bv[j] = *(const bf16x8*)(VT + (size_t)(d0 + wy * 32 + j * 16 + fr) * 4096 + g0 + kk * 32 + quad * 8);
#pragma unroll
    for (int i = 0; i < 4; i++)
#pragma unroll
      for (int j = 0; j < 2; j++)
        acc[i][j] = __builtin_amdgcn_mfma_f32_16x16x32_bf16(as[i], bv[j], acc[i][j], 0, 0, 0);
  }

#pragma unroll
  for (int i = 0; i < 4; i++)
#pragma unroll
    for (int j = 0; j < 2; j++)
#pragma unroll
      for (int r = 0; r < 4; r++) {
        int row = i * 16 + quad * 4 + r;
        int d = d0 + wy * 32 + j * 16 + fr;
        float scale = rsqrtf((float)((c * 64 + row + 1) * 64));
        R[(size_t)(g0 + row) * 256 + d] = acc[i][j][r] * scale;
      }
}

// ----------------------------------------- LayerNorm + out proj + residual
__global__ __launch_bounds__(256) void out_ln_gemm(const float* r, const float* g,
                                                   const float* bta, const float* W,
                                                   const float* ob, const float* x,
                                                   float* Y) {
  __shared__ ushort A_lds[64 * 272];
  __shared__ ushort Bs[64 * 40];
  __shared__ float gs[256], bs2[256];
  const int tid = threadIdx.x;
  const int m0 = blockIdx.x * 64, n0 = blockIdx.y * 64;
  gs[tid] = g[tid];
  bs2[tid] = bta[tid];

  const int row_l = tid >> 2, seg = (tid & 3) * 64;
  const float* rr = r + (size_t)(m0 + row_l) * 256 + seg;
  float s = 0.f, sq = 0.f;
#pragma unroll
  for (int i = 0; i < 64; i += 4) {
    float4 v = *(const float4*)(rr + i);
    s += v.x + v.y + v.z + v.w;
    sq += v.x * v.x + v.y * v.y + v.z * v.z + v.w * v.w;
  }
  s += __shfl_xor(s, 1); sq += __shfl_xor(sq, 1);
  s += __shfl_xor(s, 2); sq += __shfl_xor(sq, 2);
  float mean = s * (1.0f / 256.0f);
  float var = fmaxf(sq * (1.0f / 256.0f) - mean * mean, 0.f);
  float rstd = rsqrtf(var + 1e-5f);
  __syncthreads();
#pragma unroll
  for (int i = 0; i < 64; i += 4) {
    float4 v = *(const float4*)(rr + i);
    int k = seg + i;
    ushort4 st;
    st.x = f2bf((v.x - mean) * rstd * gs[k + 0] + bs2[k + 0]);
    st.y = f2bf((v.y - mean) * rstd * gs[k + 1] + bs2[k + 1]);
    st.z = f2bf((v.z - mean) * rstd * gs[k + 2] + bs2[k + 2]);
    st.w = f2bf((v.w - mean) * rstd * gs[k + 3] + bs2[k + 3]);
    *(ushort4*)&A_lds[row_l * 272 + k] = st;
  }
  __syncthreads();

  const int lane = tid & 63, wave = tid >> 6;
  const int wr = wave >> 1, wc = wave & 1;
  const int fr = lane & 15, quad = lane >> 4;
  const int srow = tid >> 2, sch = (tid & 3) * 8;
  f32x4 acc[2][2];
#pragma unroll
  for (int i = 0; i < 2; i++)
#pragma unroll
    for (int j = 0; j < 2; j++) acc[i][j] = (f32x4){0.f, 0.f, 0.f, 0.f};
  for (int k0 = 0; k0 < 256; k0 += 32) {
    float4 b0 = *(const float4*)(W + (size_t)(n0 + srow) * 256 + k0 + sch);
    float4 b1 = *(const float4*)(W + (size_t)(n0 + srow) * 256 + k0 + sch + 4);
    uint4 pb = { pk2(b0.x, b0.y), pk2(b0.z, b0.w), pk2(b1.x, b1.y), pk2(b1.z, b1.w) };
    *(uint4*)&Bs[srow * 40 + sch] = pb;
    __syncthreads();
    bf16x8 fa0 = *(const bf16x8*)&A_lds[(wr * 32 + fr) * 272 + k0 + quad * 8];
    bf16x8 fa1 = *(const bf16x8*)&A_lds[(wr * 32 + 16 + fr) * 272 + k0 + quad * 8];
    bf16x8 fb0 = *(const bf16x8*)&Bs[(wc * 32 + fr) * 40 + quad * 8];
    bf16x8 fb1 = *(const bf16x8*)&Bs[(wc * 32 + 16 + fr) * 40 + quad * 8];
    acc[0][0] = __builtin_amdgcn_mfma_f32_16x16x32_bf16(fa0, fb0, acc[0][0], 0, 0, 0);
    acc[0][1] = __builtin_amdgcn_mfma_f32_16x16x32_bf16(fa0, fb1, acc[0][1], 0, 0, 0);
    acc[1][0] = __builtin_amdgcn_mfma_f32_16x16x32_bf16(fa1, fb0, acc[1][0], 0, 0, 0);
    acc[1][1] = __builtin_amdgcn_mfma_f32_16x16x32_bf16(fa1, fb1, acc[1][1], 0, 0, 0);
    __syncthreads();
  }
#pragma unroll
  for (int i = 0; i < 2; i++)
#pragma unroll
    for (int j = 0; j < 2; j++) {
      int col = n0 + wc * 32 + j * 16 + fr;
      float bv = ob[col];
#pragma unroll
      for (int r = 0; r < 4; r++) {
        int rowg = m0 + wr * 32 + i * 16 + quad * 4 + r;
        Y[(size_t)rowg * 256 + col] = acc[i][j][r] + bv + x[(size_t)rowg * 256 + col];
      }
    }
}

// ------------------------------------------------------------------- launch
extern "C" void kernel_launch(void* const* d_in, const int* in_sizes, int n_in,
                              void* d_out, int out_size, void* d_ws, size_t ws_size,
                              hipStream_t stream) {
  const float* x     = (const float*)d_in[0];
  const float* kp_w1 = (const float*)d_in[1];
  const float* kp_b1 = (const float*)d_in[2];
  const float* kp_w2 = (const float*)d_in[3];
  const float* kp_b2 = (const float*)d_in[4];
  const float* qp_w1 = (const float*)d_in[5];
  const float* qp_b1 = (const float*)d_in[6];
  const float* qp_w2 = (const float*)d_in[7];
  const float* qp_b2 = (const float*)d_in[8];
  const float* kh_w1 = (const float*)d_in[9];
  const float* kh_b1 = (const float*)d_in[10];
  const float* kh_w2 = (const float*)d_in[11];
  const float* kh_b2 = (const float*)d_in[12];
  const float* qh_w1 = (const float*)d_in[13];
  const float* qh_b1 = (const float*)d_in[14];
  const float* qh_w2 = (const float*)d_in[15];
  const float* qh_b2 = (const float*)d_in[16];
  const float* v_w   = (const float*)d_in[17];
  const float* v_b   = (const float*)d_in[18];
  const float* ln_g  = (const float*)d_in[19];
  const float* ln_b  = (const float*)d_in[20];
  const float* out_w = (const float*)d_in[21];
  const float* out_b = (const float*)d_in[22];

  char* ws = (char*)d_ws;
  const size_t MiB = 1024 * 1024;
  ushort* h0   = (ushort*)(ws + 0);            // [4096][256] bf16, 2 MiB each
  ushort* h1   = (ushort*)(ws + 2 * MiB);
  ushort* h2   = (ushort*)(ws + 4 * MiB);
  ushort* h3   = (ushort*)(ws + 6 * MiB);
  ushort* VT   = (ushort*)(ws + 8 * MiB);      // [256][4096] bf16, 2 MiB
  uint*   PhiQ = (uint*)(ws + 10 * MiB);       // [4096][64] packed, 1 MiB
  uint*   PhiK = (uint*)(ws + 11 * MiB);       // 1 MiB
  uint*   PhiKT= (uint*)(ws + 12 * MiB);       // [4][128][512], 1 MiB
  ushort* SpreB= (ushort*)(ws + 25 * MiB);     // [64][256][128] bf16, 4 MiB
  float*  r    = (float*)(ws + 29 * MiB);      // [4096][256] fp32, 4 MiB

  // 1) first layers + V projection (fp32 inputs, in-kernel cast)
  G1Args g1;
  g1.p[0] = { x, kp_w1, kp_b1, h0, 1 };
  g1.p[1] = { x, qp_w1, qp_b1, h1, 1 };
  g1.p[2] = { x, kh_w1, kh_b1, h2, 1 };
  g1.p[3] = { x, qh_w1, qh_b1, h3, 1 };
  g1.p[4] = { x, v_w,   v_b,   VT, 4 };
  gemm1<<<dim3(64, 4, 5), 256, 0, stream>>>(g1);

  // 2) second layers + phasors + PhiKT, z-parallel (N=64 padded)
  const float PI_F = 3.14159265358979323846f;
  G2Args g2;
  g2.p[0] = { h0, kp_w2, kp_b2, PhiK, 48, PI_F, 1, 0 };
  g2.p[1] = { h1, qp_w2, qp_b2, PhiQ, 48, PI_F, 0, 0 };
  g2.p[2] = { h2, kh_w2, kh_b2, PhiK, 32, 0.9f, 1, 1 };
  g2.p[3] = { h3, qh_w2, qh_b2, PhiQ, 32, 0.9f, 0, 1 };
  gemm2p<<<dim3(64, 1, 4), 256, 0, stream>>>(g2, PhiKT);

  // 3) per-chunk KV sums + exclusive chunk prefix (fused, registers carry)
  kv_prefix<<<dim3(64, 2), 256, 0, stream>>>(VT, (const ushort*)PhiKT, SpreB);

  // 4) retrieve (MFMA)
  retrieve<<<dim3(64, 2), 256, 0, stream>>>((const ushort*)PhiQ, (const ushort*)PhiK,
                                            VT, SpreB, r);

  // 5) LayerNorm + out projection + residual
  out_ln_gemm<<<dim3(64, 4), 256, 0, stream>>>(r, ln_g, ln_b, out_w, out_b, x,
                                               (float*)d_out);
}